// Round 1
// baseline (9.721 us; speedup 1.0000x reference)
//
#include <hip/hip_runtime.h>

// MaskNeighborSampler: per batch row, gather a 64-wide temporal adjacency row,
// count valid (ts < t) prefix, draw S bounded samples with pre-drawn uniforms.
//
// Mapping: one 64-lane wave per batch row.
//   lane j holds adj_row[j], ts_row[j]  (coalesced 256B row loads)
//   count = popcount(ballot(ts_row[j] < t))
//   sample s (lanes 0..31): col = min((int)(u*err), err-1); values fetched via
//   __shfl from lane `col` -- no second gather from global.
//
// Output layout (single float32 buffer, tuple concatenated):
//   d_out[0        .. B*S-1] = neighbors (int ids, exact in f32: id < 2^24)
//   d_out[B*S      .. 2BS-1] = ts values

#define MAX_DEG 64

__global__ __launch_bounds__(256) void MaskNeighborSampler_kernel(
    const int* __restrict__ ids,
    const float* __restrict__ tss,
    const int* __restrict__ adj,
    const float* __restrict__ tsi,
    const float* __restrict__ u,
    float* __restrict__ out_nbr,
    float* __restrict__ out_ts,
    int B, int S) {
  const int gtid = blockIdx.x * blockDim.x + threadIdx.x;
  const int row  = gtid >> 6;           // one wave (64 lanes) per batch row
  const int lane = threadIdx.x & 63;
  if (row >= B) return;

  const int   id = ids[row];
  const float t  = tss[row];
  const long long base = (long long)id * MAX_DEG;

  // coalesced row loads: lane j owns element j of the row
  const int   adjv = adj[base + lane];
  const float tsv  = tsi[base + lane];

  // valid-prefix count: strict f32 compare, ballot across all 64 lanes
  const unsigned long long m = __ballot(tsv < t);
  const int count = __popcll(m);
  const int err   = count > 0 ? count : 1;
  const float errf = (float)err;

  // every lane computes a sample index (lanes 32..63 duplicate 0..31 so all
  // lanes participate uniformly in the shuffles)
  const int   sidx = lane & (S - 1);    // S is a power of two (32)
  const float uu   = u[(long long)row * S + sidx];
  int col = (int)(uu * errf);           // same IEEE mul+trunc as the reference
  const int cmax = err - 1;
  if (col > cmax) col = cmax;

  const int   nb = __shfl(adjv, col, 64);
  const float tv = __shfl(tsv,  col, 64);

  if (lane < S) {
    const long long o = (long long)row * S + lane;
    const bool valid = count > 0;
    out_nbr[o] = valid ? (float)nb : 0.0f;
    out_ts[o]  = valid ? tv        : 0.0f;
  }
}

extern "C" void kernel_launch(void* const* d_in, const int* in_sizes, int n_in,
                              void* d_out, int out_size, void* d_ws, size_t ws_size,
                              hipStream_t stream) {
  const int*   ids = (const int*)  d_in[0];
  const float* tss = (const float*)d_in[1];
  const int*   adj = (const int*)  d_in[2];
  const float* tsi = (const float*)d_in[3];
  const float* u   = (const float*)d_in[4];
  // d_in[5] = batch_size scalar, d_in[6] = num_samples scalar (device); use in_sizes
  const int B = in_sizes[0];
  const int S = in_sizes[4] / B;        // 32

  float* out_nbr = (float*)d_out;
  float* out_ts  = out_nbr + (long long)B * S;

  const int threads = 256;              // 4 waves = 4 rows per block
  const int rows_per_block = threads / 64;
  const int grid = (B + rows_per_block - 1) / rows_per_block;
  MaskNeighborSampler_kernel<<<grid, threads, 0, stream>>>(
      ids, tss, adj, tsi, u, out_nbr, out_ts, B, S);
}